// Round 9
// baseline (29.224 us; speedup 1.0000x reference)
//
#include <hip/hip_runtime.h>

typedef _Float16 f16;
typedef _Float16 f16x8 __attribute__((ext_vector_type(8)));
typedef float    f32x4 __attribute__((ext_vector_type(4)));

// Weight-fragment buffer (f16, built once by prep_kernel in d_ws).
// 18 KB total -> fits in each CU's 32 KB L1; MFMA B-operands are read
// DIRECTLY from global (L1-hot) — no LDS staging.
//   WF1: [5 nt][64 lane][8 j] = 2560  (GEMM1 B: W1T, K 20->32; k==20 carries b1)
//   WF2: [3 ks][3 nt][64][8]  = 4608  (GEMM2 B: W2T, K 80->96, N 40->48; k==80 carries b2)
//   WF3: [2 ks][2 nt][64][8]  = 2048  (GEMM3 B: W3T, K 40->64, N 21->32; k==40 carries b3)
#define WF1_OFF 0
#define WF2_OFF 2560
#define WF3_OFF 7168
#define WF_TOTAL 9216
#define WAVES 4
#define H_STRIDE 3072   // bytes per wave: h1 tile [12 gg][16 row][8 k] f16 = 3072B
                        // h2 tile [8 gg][16][8] = 2048B UNION'd onto the same base

// Fragment k-map convention: lane l supplies k = (l>>4)*8 + j for BOTH A and B
// fragments (contraction invariant to HW intra-lane k-permutation).
// C/D layout (m89-verified, confirmed rounds 5-8): col = lane&15, row = (lane>>4)*4 + r.
__global__ void prep_kernel(const float* __restrict__ W1, const float* __restrict__ b1,
                            const float* __restrict__ W2, const float* __restrict__ b2,
                            const float* __restrict__ W3, const float* __restrict__ b3,
                            f16* __restrict__ wf) {
    const int t0 = blockIdx.x * blockDim.x + threadIdx.x;
    const int stride = gridDim.x * blockDim.x;
    for (int idx = t0; idx < 5 * 512; idx += stride) {
        int j = idx & 7, l = (idx >> 3) & 63, nt = idx >> 9;
        int nn = nt * 16 + (l & 15);
        int k  = (l >> 4) * 8 + j;
        float v = (k < 20) ? W1[nn * 20 + k] : (k == 20 ? b1[nn] : 0.f);
        wf[WF1_OFF + idx] = (f16)v;
    }
    for (int idx = t0; idx < 9 * 512; idx += stride) {
        int j = idx & 7, l = (idx >> 3) & 63, grp = idx >> 9;
        int nt = grp % 3, ks = grp / 3;
        int nn = nt * 16 + (l & 15);
        int k  = ks * 32 + (l >> 4) * 8 + j;
        float v = 0.f;
        if (nn < 40) { if (k < 80) v = W2[nn * 80 + k]; else if (k == 80) v = b2[nn]; }
        wf[WF2_OFF + idx] = (f16)v;
    }
    for (int idx = t0; idx < 4 * 512; idx += stride) {
        int j = idx & 7, l = (idx >> 3) & 63, grp = idx >> 9;
        int nt = grp & 1, ks = grp >> 1;
        int nn = nt * 16 + (l & 15);
        int k  = ks * 32 + (l >> 4) * 8 + j;
        float v = 0.f;
        if (nn < 21) { if (k < 40) v = W3[nn * 40 + k]; else if (k == 40) v = b3[nn]; }
        wf[WF3_OFF + idx] = (f16)v;
    }
}

// One block = 64 events, 17.4 KB LDS + <=64 VGPR -> 8 blocks/CU (32 waves, 100%).
// Phase 1: VALU scores from x (lane stride 48B). Phase 2: fused 3-GEMM f16 MFMA.
// h1/h2 tiles share one union buffer per wave: every h2 write data-depends on
// acc2 (i.e. on ALL h1 A-reads), so the overlap is hazard-free by dataflow.
__global__ __launch_bounds__(256, 8) void fused_kernel(
    const float* __restrict__ x,    // [N*20*12]
    const float* __restrict__ Wl,   // [12,2]
    const float* __restrict__ bl,   // [2]
    const f16*   __restrict__ wf,   // [WF_TOTAL]
    float* __restrict__ out,        // [N,21]
    int n)
{
    __shared__ __align__(16) f16 s_lds[64][40];          // scores; col20=1.0 (bias), 21..31=0
    __shared__ __align__(16) char hbuf[WAVES * H_STRIDE];

    const int tid  = threadIdx.x;
    const int wave = tid >> 6;
    const int lane = tid & 63;
    const int lrow = lane & 15;   // A row (event) / B,C col
    const int lg   = lane >> 4;   // k-group / C row-group

    char* hb = hbuf + wave * H_STRIDE;   // wave-private h-tile base
    // h row address: (gg*16 + row) * 16 bytes   (16B per row-slice -> b128-aligned)

    // ---- h1 K-pad init: gg 10,11 zero + bias row (k==80) = 1.0 ----
    {
        int* z1 = reinterpret_cast<int*>(hb + 2560);     // bytes 2560..3071
        z1[lane] = 0; z1[lane + 64] = 0;
        if (lane < 16) *reinterpret_cast<f16*>(hb + (10 * 16 + lane) * 16) = (f16)1.f;
    }

    // ---- score K-pad: col 20 = 1.0 (bias lane), 21..31 = 0, all 64 rows ----
#pragma unroll
    for (int it = 0; it < 3; ++it) {
        int idx = it * 256 + tid;                // 768 = 64 rows x 12 cols
        int row = idx / 12, c = idx % 12;
        s_lds[row][20 + c] = (c == 0) ? (f16)1.f : (f16)0.f;
    }

    // ---- phase 1: triplet scores, lane-stride-48B loads ----
    float wl[12];
#pragma unroll
    for (int f = 0; f < 12; ++f) wl[f] = Wl[f * 2 + 1];
    const float blv = bl[1];

    const int n_trip = n * 20;
    const int trip_base = blockIdx.x * 1280;
#pragma unroll
    for (int r = 0; r < 5; ++r) {
        const int bt = r * 256 + tid;            // block-local triplet 0..1279
        const int trip = trip_base + bt;
        if (trip < n_trip) {
            const float4* xt = reinterpret_cast<const float4*>(x + (size_t)trip * 12);
            float4 a0 = xt[0], a1 = xt[1], a2 = xt[2];
            float acc = blv;
            acc += a0.x*wl[0] + a0.y*wl[1] + a0.z*wl[2]  + a0.w*wl[3];
            acc += a1.x*wl[4] + a1.y*wl[5] + a1.z*wl[6]  + a1.w*wl[7];
            acc += a2.x*wl[8] + a2.y*wl[9] + a2.z*wl[10] + a2.w*wl[11];
            s_lds[bt / 20][bt % 20] = (f16)acc;
        }
    }

    __syncthreads();

    const int ev0 = blockIdx.x * (WAVES * 16) + wave * 16;
    if (ev0 >= n) return;   // n % 16 == 0 -> wave fully valid or fully out

    const f16x8* bfrag = reinterpret_cast<const f16x8*>(wf);   // global, L1-hot
    const f32x4 zero4 = {0.f, 0.f, 0.f, 0.f};

    // ---- GEMM1: [16 ev x 32k] x [32k x 80]  (bias in k=20) ----
    f16x8 a1 = *reinterpret_cast<const f16x8*>(&s_lds[wave * 16 + lrow][lg * 8]);
    f32x4 acc1[5];
#pragma unroll
    for (int nt = 0; nt < 5; ++nt)
        acc1[nt] = __builtin_amdgcn_mfma_f32_16x16x32_f16(
            a1, bfrag[(WF1_OFF / 8) + nt * 64 + lane], zero4, 0, 0, 0);
#pragma unroll
    for (int nt = 0; nt < 5; ++nt) {
        const int neuron = nt * 16 + lrow;
#pragma unroll
        for (int r = 0; r < 4; ++r) {
            float v = fmaxf(acc1[nt][r], 0.f);
            reinterpret_cast<f16*>(hb + ((neuron >> 3) * 16 + lg * 4 + r) * 16)[neuron & 7] = (f16)v;
        }
    }
    // wave-private tile: same-wave DS ordering + compiler lgkmcnt suffice (rounds 5-8 verified)

    // ---- GEMM2: [16 x 96k] x [96k x 48]  (bias in k=80) ----
    f32x4 acc2[3] = {zero4, zero4, zero4};
#pragma unroll
    for (int ks = 0; ks < 3; ++ks) {
        f16x8 a = *reinterpret_cast<const f16x8*>(hb + ((ks * 4 + lg) * 16 + lrow) * 16);
#pragma unroll
        for (int nt = 0; nt < 3; ++nt)
            acc2[nt] = __builtin_amdgcn_mfma_f32_16x16x32_f16(
                a, bfrag[(WF2_OFF / 8) + (ks * 3 + nt) * 64 + lane], acc2[nt], 0, 0, 0);
    }

    // ---- h2 K-pad init (AFTER all h1 reads; aliases old h1 k=40..63): ----
    {
        int* z2 = reinterpret_cast<int*>(hb + 1280);     // gg 5,6,7: bytes 1280..2047
        z2[lane] = 0; z2[lane + 64] = 0; z2[lane + 128] = 0;
        if (lane < 16) *reinterpret_cast<f16*>(hb + (5 * 16 + lane) * 16) = (f16)1.f;  // k==40
    }
#pragma unroll
    for (int nt = 0; nt < 3; ++nt) {
        const int nn = nt * 16 + lrow;
#pragma unroll
        for (int r = 0; r < 4; ++r) {
            float v = fmaxf(acc2[nt][r], 0.f);
            if (nn < 40)
                reinterpret_cast<f16*>(hb + ((nn >> 3) * 16 + lg * 4 + r) * 16)[nn & 7] = (f16)v;
        }
    }

    // ---- GEMM3: [16 x 64k] x [64k x 32]  (bias in k=40) ----
    f32x4 acc3[2] = {zero4, zero4};
#pragma unroll
    for (int ks = 0; ks < 2; ++ks) {
        f16x8 a = *reinterpret_cast<const f16x8*>(hb + ((ks * 4 + lg) * 16 + lrow) * 16);
#pragma unroll
        for (int nt = 0; nt < 2; ++nt)
            acc3[nt] = __builtin_amdgcn_mfma_f32_16x16x32_f16(
                a, bfrag[(WF3_OFF / 8) + (ks * 2 + nt) * 64 + lane], acc3[nt], 0, 0, 0);
    }
#pragma unroll
    for (int nt = 0; nt < 2; ++nt) {
        const int col = nt * 16 + lrow;
        if (col < 21) {
#pragma unroll
            for (int r = 0; r < 4; ++r)
                out[(size_t)(ev0 + lg * 4 + r) * 21 + col] = acc3[nt][r];
        }
    }
}

extern "C" void kernel_launch(void* const* d_in, const int* in_sizes, int n_in,
                              void* d_out, int out_size, void* d_ws, size_t ws_size,
                              hipStream_t stream) {
    const float* x  = (const float*)d_in[0];
    const float* Wl = (const float*)d_in[1];
    const float* bl = (const float*)d_in[2];
    const float* W1 = (const float*)d_in[3];
    const float* b1 = (const float*)d_in[4];
    const float* W2 = (const float*)d_in[5];
    const float* b2 = (const float*)d_in[6];
    const float* W3 = (const float*)d_in[7];
    const float* b3 = (const float*)d_in[8];
    float* out = (float*)d_out;

    const int n = in_sizes[0] / 240;       // events (100000)
    f16* wf = (f16*)d_ws;                  // [WF_TOTAL] f16 = 18 KB

    prep_kernel<<<16, 256, 0, stream>>>(W1, b1, W2, b2, W3, b3, wf);

    const int grid = (n + 63) / 64;        // 64 events per block
    fused_kernel<<<grid, 256, 0, stream>>>(x, Wl, bl, wf, out, n);
}